// Round 1
// baseline (133.922 us; speedup 1.0000x reference)
//
#include <hip/hip_runtime.h>
#include <math.h>

#define BB 4
#define NN 4096
#define MM 4096
#define TI 128
#define TJ 128
#define NTI (NN / TI)   // 32
#define NTJ (MM / TJ)   // 32

#define L2E100 144.26950408889634f   // 100 * log2(e); exp(-100*d) = exp2(-L2E100*d)

// workspace layout (floats):
// [0,16384)      m2_row  (min d^2 over j, per (b,i))  -- stored as float bits, used as uint
// [16384,32768)  m2_col  (min d^2 over i, per (b,j))
// [32768,49152)  num_r
// [49152,65536)  den_r
// [65536,81920)  num_c
// [81920,98304)  den_c

__global__ __launch_bounds__(256)
void init_ws_kernel(float* ws) {
    int idx = blockIdx.x * 256 + threadIdx.x;
    if (idx < 2 * 16384) ws[idx] = 1e30f;
    else if (idx < 6 * 16384) ws[idx] = 0.0f;
}

__global__ __launch_bounds__(256)
void pass1_min(const float* __restrict__ x, const float* __restrict__ y,
               unsigned int* __restrict__ m2_row, unsigned int* __restrict__ m2_col) {
    const int bid = blockIdx.x;
    const int b   = bid / (NTI * NTJ);
    const int rem = bid % (NTI * NTJ);
    const int i0  = (rem / NTJ) * TI;
    const int j0  = (rem % NTJ) * TJ;

    __shared__ float xs[TI * 3];
    __shared__ float ys[TJ * 3];
    __shared__ unsigned int cmin_s[TJ];

    const int t = threadIdx.x;
    for (int k = t; k < TI * 3; k += 256) xs[k] = x[(size_t)(b * NN + i0) * 3 + k];
    for (int k = t; k < TJ * 3; k += 256) ys[k] = y[(size_t)(b * MM + j0) * 3 + k];
    if (t < TJ) cmin_s[t] = 0x7F7FFFFFu;  // FLT_MAX bits (nonneg float ordering == uint ordering)
    __syncthreads();

    const int tx = t & 15, ty = t >> 4;
    float xi0[8], xi1[8], xi2[8], yj0[8], yj1[8], yj2[8];
#pragma unroll
    for (int k = 0; k < 8; ++k) {
        int i = ty + k * 16;
        xi0[k] = xs[i * 3 + 0]; xi1[k] = xs[i * 3 + 1]; xi2[k] = xs[i * 3 + 2];
    }
#pragma unroll
    for (int l = 0; l < 8; ++l) {
        int j = tx + l * 16;
        yj0[l] = ys[j * 3 + 0]; yj1[l] = ys[j * 3 + 1]; yj2[l] = ys[j * 3 + 2];
    }
    float rmin[8], cmin[8];
#pragma unroll
    for (int k = 0; k < 8; ++k) { rmin[k] = 1e30f; cmin[k] = 1e30f; }

#pragma unroll
    for (int k = 0; k < 8; ++k) {
#pragma unroll
        for (int l = 0; l < 8; ++l) {
            float dx = xi0[k] - yj0[l];
            float dy = xi1[k] - yj1[l];
            float dz = xi2[k] - yj2[l];
            float d2 = fmaf(dx, dx, fmaf(dy, dy, dz * dz));
            rmin[k] = fminf(rmin[k], d2);
            cmin[l] = fminf(cmin[l], d2);
        }
    }

    // row mins: reduce across tx (contiguous 16-lane groups within a wave)
#pragma unroll
    for (int k = 0; k < 8; ++k) {
        float v = rmin[k];
        v = fminf(v, __shfl_xor(v, 1));
        v = fminf(v, __shfl_xor(v, 2));
        v = fminf(v, __shfl_xor(v, 4));
        v = fminf(v, __shfl_xor(v, 8));
        if (tx == 0) atomicMin(&m2_row[b * NN + i0 + ty + k * 16], __float_as_uint(v));
    }
    // col mins: reduce across ty. Within a wave: ty quad via xor 16,32; then LDS atomics across waves.
#pragma unroll
    for (int l = 0; l < 8; ++l) {
        float v = cmin[l];
        v = fminf(v, __shfl_xor(v, 16));
        v = fminf(v, __shfl_xor(v, 32));
        if ((t & 63) < 16) atomicMin(&cmin_s[tx + l * 16], __float_as_uint(v));
    }
    __syncthreads();
    if (t < TJ) atomicMin(&m2_col[b * MM + j0 + t], cmin_s[t]);
}

__global__ __launch_bounds__(256)
void pass2_acc(const float* __restrict__ x, const float* __restrict__ y,
               const unsigned int* __restrict__ m2_row, const unsigned int* __restrict__ m2_col,
               float* __restrict__ num_r, float* __restrict__ den_r,
               float* __restrict__ num_c, float* __restrict__ den_c) {
    const int bid = blockIdx.x;
    const int b   = bid / (NTI * NTJ);
    const int rem = bid % (NTI * NTJ);
    const int i0  = (rem / NTJ) * TI;
    const int j0  = (rem % NTJ) * TJ;

    __shared__ float xs[TI * 3];
    __shared__ float ys[TJ * 3];
    __shared__ float ar[TI];   // L2E100 * sqrt(m2_row)
    __shared__ float ac[TJ];
    __shared__ float snc[TJ], sdc[TJ];

    const int t = threadIdx.x;
    for (int k = t; k < TI * 3; k += 256) xs[k] = x[(size_t)(b * NN + i0) * 3 + k];
    for (int k = t; k < TJ * 3; k += 256) ys[k] = y[(size_t)(b * MM + j0) * 3 + k];
    if (t < TI) ar[t] = L2E100 * sqrtf(__uint_as_float(m2_row[b * NN + i0 + t]));
    if (t < TJ) {
        ac[t] = L2E100 * sqrtf(__uint_as_float(m2_col[b * MM + j0 + t]));
        snc[t] = 0.0f; sdc[t] = 0.0f;
    }
    __syncthreads();

    const int tx = t & 15, ty = t >> 4;
    float xi0[8], xi1[8], xi2[8], yj0[8], yj1[8], yj2[8], sr[8], sc[8];
#pragma unroll
    for (int k = 0; k < 8; ++k) {
        int i = ty + k * 16;
        xi0[k] = xs[i * 3 + 0]; xi1[k] = xs[i * 3 + 1]; xi2[k] = xs[i * 3 + 2];
        sr[k] = ar[i];
    }
#pragma unroll
    for (int l = 0; l < 8; ++l) {
        int j = tx + l * 16;
        yj0[l] = ys[j * 3 + 0]; yj1[l] = ys[j * 3 + 1]; yj2[l] = ys[j * 3 + 2];
        sc[l] = ac[j];
    }
    float nr[8], dr[8], nc[8], dc[8];
#pragma unroll
    for (int k = 0; k < 8; ++k) { nr[k] = 0.f; dr[k] = 0.f; nc[k] = 0.f; dc[k] = 0.f; }

#pragma unroll
    for (int k = 0; k < 8; ++k) {
#pragma unroll
        for (int l = 0; l < 8; ++l) {
            float dx = xi0[k] - yj0[l];
            float dy = xi1[k] - yj1[l];
            float dz = xi2[k] - yj2[l];
            float d2 = fmaf(dx, dx, fmaf(dy, dy, dz * dz));
            float d  = sqrtf(d2);
            float er = exp2f(fmaf(d, -L2E100, sr[k]));   // exp(-100*(d - m_row))
            float ec = exp2f(fmaf(d, -L2E100, sc[l]));   // exp(-100*(d - m_col))
            nr[k] = fmaf(d, er, nr[k]);  dr[k] += er;
            nc[l] = fmaf(d, ec, nc[l]);  dc[l] += ec;
        }
    }

    // rows: shuffle-reduce across tx, then global atomics (1 per (row,block))
#pragma unroll
    for (int k = 0; k < 8; ++k) {
        float vn = nr[k], vd = dr[k];
#pragma unroll
        for (int m = 1; m <= 8; m <<= 1) { vn += __shfl_xor(vn, m); vd += __shfl_xor(vd, m); }
        if (tx == 0) {
            atomicAdd(&num_r[b * NN + i0 + ty + k * 16], vn);
            atomicAdd(&den_r[b * NN + i0 + ty + k * 16], vd);
        }
    }
    // cols: wave-level reduce over ty quads, LDS combine across waves, then global atomics
#pragma unroll
    for (int l = 0; l < 8; ++l) {
        float vn = nc[l], vd = dc[l];
        vn += __shfl_xor(vn, 16); vd += __shfl_xor(vd, 16);
        vn += __shfl_xor(vn, 32); vd += __shfl_xor(vd, 32);
        if ((t & 63) < 16) { atomicAdd(&snc[tx + l * 16], vn); atomicAdd(&sdc[tx + l * 16], vd); }
    }
    __syncthreads();
    if (t < TJ) {
        atomicAdd(&num_c[b * MM + j0 + t], snc[t]);
        atomicAdd(&den_c[b * MM + j0 + t], sdc[t]);
    }
}

__global__ __launch_bounds__(256)
void finalize_kernel(const float* __restrict__ num_r, const float* __restrict__ den_r,
                     const float* __restrict__ num_c, const float* __restrict__ den_c,
                     float* __restrict__ out) {
    const int t = threadIdx.x;
    float s = 0.0f;
    for (int idx = t; idx < BB * NN; idx += 256) {
        s += num_r[idx] / den_r[idx];
        s += num_c[idx] / den_c[idx];
    }
#pragma unroll
    for (int m = 1; m < 64; m <<= 1) s += __shfl_xor(s, m);
    __shared__ float wsum[4];
    if ((t & 63) == 0) wsum[t >> 6] = s;
    __syncthreads();
    if (t == 0) out[0] = (wsum[0] + wsum[1] + wsum[2] + wsum[3]) / (float)(BB * NN);
}

extern "C" void kernel_launch(void* const* d_in, const int* in_sizes, int n_in,
                              void* d_out, int out_size, void* d_ws, size_t ws_size,
                              hipStream_t stream) {
    const float* x = (const float*)d_in[0];
    const float* y = (const float*)d_in[1];
    float* ws = (float*)d_ws;

    unsigned int* m2_row = (unsigned int*)(ws);
    unsigned int* m2_col = (unsigned int*)(ws + 16384);
    float* num_r = ws + 32768;
    float* den_r = ws + 49152;
    float* num_c = ws + 65536;
    float* den_c = ws + 81920;

    hipLaunchKernelGGL(init_ws_kernel, dim3(384), dim3(256), 0, stream, ws);
    dim3 grid(BB * NTI * NTJ);  // 4096 blocks
    hipLaunchKernelGGL(pass1_min, grid, dim3(256), 0, stream, x, y, m2_row, m2_col);
    hipLaunchKernelGGL(pass2_acc, grid, dim3(256), 0, stream,
                       x, y, m2_row, m2_col, num_r, den_r, num_c, den_c);
    hipLaunchKernelGGL(finalize_kernel, dim3(1), dim3(256), 0, stream,
                       num_r, den_r, num_c, den_c, (float*)d_out);
}

// Round 2
// 94.792 us; speedup vs baseline: 1.4128x; 1.4128x over previous
//
#include <hip/hip_runtime.h>
#include <math.h>

#define BB 4
#define NN 4096
#define MM 4096
#define TI 128
#define TJ 128
#define NTI (NN / TI)   // 32
#define NTJ (MM / TJ)   // 32

#define L2E100 144.26950408889634f   // 100 * log2(e); exp(-100*d) = exp2(-L2E100*d)

// workspace layout (floats):
// [0,16384)      m2_row  (min d^2 over j, per (b,i))  -- float bits, used as uint
// [16384,32768)  m2_col  (min d^2 over i, per (b,j))
// [32768,49152)  num_r
// [49152,65536)  den_r
// [65536,81920)  num_c
// [81920,98304)  den_c

__global__ __launch_bounds__(256)
void init_ws_kernel(float* ws, float* out) {
    int idx = blockIdx.x * 256 + threadIdx.x;
    if (idx < 2 * 16384) ws[idx] = 1e30f;
    else if (idx < 6 * 16384) ws[idx] = 0.0f;
    if (idx == 0) out[0] = 0.0f;
}

__global__ __launch_bounds__(256)
void pass1_min(const float* __restrict__ x, const float* __restrict__ y,
               unsigned int* __restrict__ m2_row, unsigned int* __restrict__ m2_col) {
    const int bid = blockIdx.x;
    const int b   = bid / (NTI * NTJ);
    const int rem = bid % (NTI * NTJ);
    const int i0  = (rem / NTJ) * TI;
    const int j0  = (rem % NTJ) * TJ;

    __shared__ float xs[TI * 3];
    __shared__ float ys[TJ * 3];
    __shared__ unsigned int cmin_s[TJ];

    const int t = threadIdx.x;
    for (int k = t; k < TI * 3; k += 256) xs[k] = x[(size_t)(b * NN + i0) * 3 + k];
    for (int k = t; k < TJ * 3; k += 256) ys[k] = y[(size_t)(b * MM + j0) * 3 + k];
    if (t < TJ) cmin_s[t] = 0x7F7FFFFFu;  // FLT_MAX bits
    __syncthreads();

    const int tx = t & 15, ty = t >> 4;
    float xi0[8], xi1[8], xi2[8], yj0[8], yj1[8], yj2[8];
#pragma unroll
    for (int k = 0; k < 8; ++k) {
        int i = ty + k * 16;
        xi0[k] = xs[i * 3 + 0]; xi1[k] = xs[i * 3 + 1]; xi2[k] = xs[i * 3 + 2];
    }
#pragma unroll
    for (int l = 0; l < 8; ++l) {
        int j = tx + l * 16;
        yj0[l] = ys[j * 3 + 0]; yj1[l] = ys[j * 3 + 1]; yj2[l] = ys[j * 3 + 2];
    }
    float rmin[8], cmin[8];
#pragma unroll
    for (int k = 0; k < 8; ++k) { rmin[k] = 1e30f; cmin[k] = 1e30f; }

#pragma unroll
    for (int k = 0; k < 8; ++k) {
#pragma unroll
        for (int l = 0; l < 8; ++l) {
            float dx = xi0[k] - yj0[l];
            float dy = xi1[k] - yj1[l];
            float dz = xi2[k] - yj2[l];
            float d2 = fmaf(dx, dx, fmaf(dy, dy, dz * dz));
            rmin[k] = fminf(rmin[k], d2);
            cmin[l] = fminf(cmin[l], d2);
        }
    }

#pragma unroll
    for (int k = 0; k < 8; ++k) {
        float v = rmin[k];
        v = fminf(v, __shfl_xor(v, 1));
        v = fminf(v, __shfl_xor(v, 2));
        v = fminf(v, __shfl_xor(v, 4));
        v = fminf(v, __shfl_xor(v, 8));
        if (tx == 0) atomicMin(&m2_row[b * NN + i0 + ty + k * 16], __float_as_uint(v));
    }
#pragma unroll
    for (int l = 0; l < 8; ++l) {
        float v = cmin[l];
        v = fminf(v, __shfl_xor(v, 16));
        v = fminf(v, __shfl_xor(v, 32));
        if ((t & 63) < 16) atomicMin(&cmin_s[tx + l * 16], __float_as_uint(v));
    }
    __syncthreads();
    if (t < TJ) atomicMin(&m2_col[b * MM + j0 + t], cmin_s[t]);
}

__global__ __launch_bounds__(256)
void pass2_acc(const float* __restrict__ x, const float* __restrict__ y,
               const unsigned int* __restrict__ m2_row, const unsigned int* __restrict__ m2_col,
               float* __restrict__ num_r, float* __restrict__ den_r,
               float* __restrict__ num_c, float* __restrict__ den_c) {
    const int bid = blockIdx.x;
    const int b   = bid / (NTI * NTJ);
    const int rem = bid % (NTI * NTJ);
    const int i0  = (rem / NTJ) * TI;
    const int j0  = (rem % NTJ) * TJ;

    __shared__ float xs[TI * 3];
    __shared__ float ys[TJ * 3];
    __shared__ float ar[TI];   // L2E100 * sqrt(m2_row)
    __shared__ float ac[TJ];
    __shared__ float snc[TJ], sdc[TJ];

    const int t = threadIdx.x;
    for (int k = t; k < TI * 3; k += 256) xs[k] = x[(size_t)(b * NN + i0) * 3 + k];
    for (int k = t; k < TJ * 3; k += 256) ys[k] = y[(size_t)(b * MM + j0) * 3 + k];
    if (t < TI) ar[t] = L2E100 * __builtin_amdgcn_sqrtf(__uint_as_float(m2_row[b * NN + i0 + t]));
    if (t < TJ) {
        ac[t] = L2E100 * __builtin_amdgcn_sqrtf(__uint_as_float(m2_col[b * MM + j0 + t]));
        snc[t] = 0.0f; sdc[t] = 0.0f;
    }
    __syncthreads();

    const int tx = t & 15, ty = t >> 4;
    float xi0[8], xi1[8], xi2[8], yj0[8], yj1[8], yj2[8], sr[8], sc[8];
#pragma unroll
    for (int k = 0; k < 8; ++k) {
        int i = ty + k * 16;
        xi0[k] = xs[i * 3 + 0]; xi1[k] = xs[i * 3 + 1]; xi2[k] = xs[i * 3 + 2];
        sr[k] = ar[i];
    }
#pragma unroll
    for (int l = 0; l < 8; ++l) {
        int j = tx + l * 16;
        yj0[l] = ys[j * 3 + 0]; yj1[l] = ys[j * 3 + 1]; yj2[l] = ys[j * 3 + 2];
        sc[l] = ac[j];
    }
    float nr[8], dr[8], nc[8], dc[8];
#pragma unroll
    for (int k = 0; k < 8; ++k) { nr[k] = 0.f; dr[k] = 0.f; nc[k] = 0.f; dc[k] = 0.f; }

#pragma unroll
    for (int k = 0; k < 8; ++k) {
#pragma unroll
        for (int l = 0; l < 8; ++l) {
            float dx = xi0[k] - yj0[l];
            float dy = xi1[k] - yj1[l];
            float dz = xi2[k] - yj2[l];
            float d2 = fmaf(dx, dx, fmaf(dy, dy, dz * dz));
            float d  = __builtin_amdgcn_sqrtf(d2);                  // raw v_sqrt_f32
            float er = __builtin_amdgcn_exp2f(fmaf(d, -L2E100, sr[k]));  // raw v_exp_f32
            float ec = __builtin_amdgcn_exp2f(fmaf(d, -L2E100, sc[l]));
            nr[k] = fmaf(d, er, nr[k]);  dr[k] += er;
            nc[l] = fmaf(d, ec, nc[l]);  dc[l] += ec;
        }
    }

    // rows: shuffle-reduce across tx, then global atomics
#pragma unroll
    for (int k = 0; k < 8; ++k) {
        float vn = nr[k], vd = dr[k];
#pragma unroll
        for (int m = 1; m <= 8; m <<= 1) { vn += __shfl_xor(vn, m); vd += __shfl_xor(vd, m); }
        if (tx == 0) {
            atomicAdd(&num_r[b * NN + i0 + ty + k * 16], vn);
            atomicAdd(&den_r[b * NN + i0 + ty + k * 16], vd);
        }
    }
    // cols: wave reduce over ty, LDS combine across waves, then global atomics
#pragma unroll
    for (int l = 0; l < 8; ++l) {
        float vn = nc[l], vd = dc[l];
        vn += __shfl_xor(vn, 16); vd += __shfl_xor(vd, 16);
        vn += __shfl_xor(vn, 32); vd += __shfl_xor(vd, 32);
        if ((t & 63) < 16) { atomicAdd(&snc[tx + l * 16], vn); atomicAdd(&sdc[tx + l * 16], vd); }
    }
    __syncthreads();
    if (t < TJ) {
        atomicAdd(&num_c[b * MM + j0 + t], snc[t]);
        atomicAdd(&den_c[b * MM + j0 + t], sdc[t]);
    }
}

__global__ __launch_bounds__(256)
void finalize_kernel(const float* __restrict__ num_r, const float* __restrict__ den_r,
                     const float* __restrict__ num_c, const float* __restrict__ den_c,
                     float* __restrict__ out) {
    const int gid = blockIdx.x * 256 + threadIdx.x;
    float s = 0.0f;
    for (int idx = gid; idx < BB * NN; idx += 32 * 256) {
        s = fmaf(num_r[idx], __builtin_amdgcn_rcpf(den_r[idx]), s);
        s = fmaf(num_c[idx], __builtin_amdgcn_rcpf(den_c[idx]), s);
    }
#pragma unroll
    for (int m = 1; m < 64; m <<= 1) s += __shfl_xor(s, m);
    __shared__ float wsum[4];
    const int t = threadIdx.x;
    if ((t & 63) == 0) wsum[t >> 6] = s;
    __syncthreads();
    if (t == 0) {
        float v = (wsum[0] + wsum[1] + wsum[2] + wsum[3]) * (1.0f / (float)(BB * NN));
        atomicAdd(out, v);
    }
}

extern "C" void kernel_launch(void* const* d_in, const int* in_sizes, int n_in,
                              void* d_out, int out_size, void* d_ws, size_t ws_size,
                              hipStream_t stream) {
    const float* x = (const float*)d_in[0];
    const float* y = (const float*)d_in[1];
    float* ws = (float*)d_ws;

    unsigned int* m2_row = (unsigned int*)(ws);
    unsigned int* m2_col = (unsigned int*)(ws + 16384);
    float* num_r = ws + 32768;
    float* den_r = ws + 49152;
    float* num_c = ws + 65536;
    float* den_c = ws + 81920;

    hipLaunchKernelGGL(init_ws_kernel, dim3(384), dim3(256), 0, stream, ws, (float*)d_out);
    dim3 grid(BB * NTI * NTJ);  // 4096 blocks
    hipLaunchKernelGGL(pass1_min, grid, dim3(256), 0, stream, x, y, m2_row, m2_col);
    hipLaunchKernelGGL(pass2_acc, grid, dim3(256), 0, stream,
                       x, y, m2_row, m2_col, num_r, den_r, num_c, den_c);
    hipLaunchKernelGGL(finalize_kernel, dim3(32), dim3(256), 0, stream,
                       num_r, den_r, num_c, den_c, (float*)d_out);
}